// Round 9
// baseline (435.102 us; speedup 1.0000x reference)
//
#include <hip/hip_runtime.h>

#define NNODES 50000
#define NREL   8
#define HID    64
#define NCLS   16
#define NEDGE  1600000
#define NTGT   8192
#define HALF   4096
#define NBINS  (NNODES * NREL)
#define CHUNK  1024
#define NCHUNK ((NBINS + CHUNK - 1) / CHUNK)   // 391
#define NQUAD  (NEDGE / 4)                     // 400000
#define QPART  (NQUAD / 4)                     // 100000 quads per count part
#define C1PART (NNODES / 4)                    // 12500 nodes per conv1 part

__device__ __forceinline__ float elu1(float x) { return x > 0.f ? x : expm1f(x); }

// packed edge record: src[15:0] | rel[18:16] | cnt[31:19]
__device__ __forceinline__ int pack_rec(int src, int rel, int cnt) {
  return src | (rel << 16) | (cnt << 19);
}

__device__ __forceinline__ unsigned long long ld_stat(unsigned long long* p) {
  return __hip_atomic_load(p, __ATOMIC_RELAXED, __HIP_MEMORY_SCOPE_AGENT);
}
__device__ __forceinline__ void st_stat(unsigned long long* p, unsigned long long v) {
  __hip_atomic_store(p, v, __ATOMIC_RELAXED, __HIP_MEMORY_SCOPE_AGENT);
}

// --- K1: per-(dst,rel) counts; SPLIT x4 by edge range (visibility probe) -----
__global__ void count_kernel(const int* __restrict__ ei, const int* __restrict__ et,
                             int* __restrict__ cnt, int* __restrict__ epos,
                             unsigned long long* __restrict__ status, int qoff) {
  int q = blockIdx.x * blockDim.x + threadIdx.x;
  if (qoff == 0 && q < NCHUNK) status[q] = 0;  // consumed by scan_lb (after all parts)
  if (q >= QPART) return;
  int e4 = (qoff + q) * 4;
  int4 d = *(const int4*)(ei + NEDGE + e4);
  int4 r = *(const int4*)(et + e4);
  int4 p;
  p.x = atomicAdd(&cnt[d.x * NREL + r.x], 1);
  p.y = atomicAdd(&cnt[d.y * NREL + r.y], 1);
  p.z = atomicAdd(&cnt[d.z * NREL + r.z], 1);
  p.w = atomicAdd(&cnt[d.w * NREL + r.w], 1);
  *(int4*)(epos + e4) = p;
}

// --- K2: single-pass scan with decoupled lookback -> binptr -----------------
__global__ __launch_bounds__(256) void scan_lb_kernel(
    const int* __restrict__ cnt, unsigned long long* __restrict__ status,
    int* __restrict__ binptr) {
  __shared__ int sw[4];
  __shared__ int srun;
  __shared__ int sbase;
  int t = threadIdx.x, lane = t & 63, wid = t >> 6;
  int c = blockIdx.x;
  int i = c * CHUNK + t * 4;
  int4 cv = make_int4(0, 0, 0, 0);
  if (i < NBINS) cv = *(const int4*)(cnt + i);
  int p0 = cv.x, p1 = p0 + cv.y, p2 = p1 + cv.z, s = p2 + cv.w;
  int v = s;
#pragma unroll
  for (int off = 1; off < 64; off <<= 1) {
    int u = __shfl_up(v, off);
    if (lane >= off) v += u;
  }
  if (lane == 63) sw[wid] = v;
  __syncthreads();
  if (t == 0) {
    int run = 0;
#pragma unroll
    for (int j = 0; j < 4; ++j) { int x = sw[j]; sw[j] = run; run += x; }
    srun = run;
    unsigned long long f = (c == 0) ? 2ull : 1ull;
    st_stat(&status[c], (f << 62) | (unsigned)run);
    if (c == 0) sbase = 0;
  }
  __syncthreads();
  if (c > 0 && t < 64) {
    long long tot = 0;
    int back = c - 1;
    for (;;) {
      int idx = back - lane;
      unsigned long long st = (2ull << 62);
      if (idx >= 0) st = ld_stat(&status[idx]);
      int flag = (int)(st >> 62);
      bool isinc = (idx < 0) || (flag == 2);
      bool isval = (idx < 0) || (flag >= 1);
      unsigned long long incb = __ballot(isinc);
      unsigned long long valb = __ballot(isval);
      unsigned long long notval = ~valb;
      int firstinv = notval ? (__ffsll((long long)notval) - 1) : 64;
      int firstinc = incb ? (__ffsll((long long)incb) - 1) : 64;
      if (firstinc < firstinv) {
        int val = (lane <= firstinc) ? (int)(st & 0xFFFFFFFFu) : 0;
#pragma unroll
        for (int off = 32; off >= 1; off >>= 1) val += __shfl_xor(val, off);
        tot += val;
        break;
      } else if (firstinv > 0) {
        int val = (lane < firstinv) ? (int)(st & 0xFFFFFFFFu) : 0;
#pragma unroll
        for (int off = 32; off >= 1; off >>= 1) val += __shfl_xor(val, off);
        tot += val;
        back -= firstinv;
      } else {
        __builtin_amdgcn_s_sleep(2);
      }
    }
    if (lane == 0) {
      sbase = (int)tot;
      st_stat(&status[c], (2ull << 62) | (unsigned)((int)tot + srun));
    }
  }
  __syncthreads();
  int base = sbase;
  if (i < NBINS) {
    int excl = base + sw[wid] + (v - s);
    *(int4*)(binptr + i) = make_int4(excl, excl + p0, excl + p1, excl + p2);
  }
  if (c == 0 && t == 0) binptr[NBINS] = NEDGE;
}

// --- K3: scatter -> epo[pos] = packed {src,rel,cnt} (4 B) --------------------
__global__ void scatter_kernel(const int* __restrict__ ei, const int* __restrict__ et,
                               const int* __restrict__ epos, const int* __restrict__ binptr,
                               int* __restrict__ epo) {
  int e4 = (blockIdx.x * blockDim.x + threadIdx.x) * 4;
  if (e4 >= NEDGE) return;
  int4 sv = *(const int4*)(ei + e4);
  int4 dv = *(const int4*)(ei + NEDGE + e4);
  int4 rv = *(const int4*)(et + e4);
  int4 pv = *(const int4*)(epos + e4);
  int srcs[4] = {sv.x, sv.y, sv.z, sv.w};
  int dsts[4] = {dv.x, dv.y, dv.z, dv.w};
  int rels[4] = {rv.x, rv.y, rv.z, rv.w};
  int poss[4] = {pv.x, pv.y, pv.z, pv.w};
#pragma unroll
  for (int j = 0; j < 4; ++j) {
    int bin = dsts[j] * NREL + rels[j];
    int b = binptr[bin];
    int c = binptr[bin + 1] - b;  // c >= 1, < 2^13
    epo[b + poss[j]] = pack_rec(srcs[j], rels[j], c);
  }
}

// --- K4: conv1 — wave per node; SPLIT x4 by node range (visibility probe) ----
__global__ __launch_bounds__(256) void conv1_kernel(
    const int* __restrict__ binptr, const int* __restrict__ epo,
    const float* __restrict__ w1, const float* __restrict__ root1,
    const float* __restrict__ bias1, float* __restrict__ h1, int nodeOff) {
  int wave = nodeOff + blockIdx.x * 4 + (threadIdx.x >> 6);
  if (wave >= NNODES) return;
  int lane = threadIdx.x & 63;
  int g = lane >> 4;            // edge subgroup 0..3
  int col = (lane & 15) << 2;   // float4 column offset
  int b0 = binptr[wave * NREL], b8 = binptr[wave * NREL + NREL];
  float4 acc = make_float4(0.f, 0.f, 0.f, 0.f);
  for (int eb = b0; eb < b8; eb += 64) {
    int mb = min(64, b8 - eb);
    int q = epo[eb + min(lane, mb - 1)];
    for (int j = 0; j < mb; j += 32) {  // superbatch: 8 slots x 4 edges
      float4 a[8]; float sc[8];
#pragma unroll
      for (int u = 0; u < 8; ++u) {
        int e0 = j + u * 4;
        if (e0 < mb) {                       // wave-uniform branch
          int ei = e0 + g;
          int eic = min(ei, mb - 1);
          int rec = __shfl(q, eic);
          int src = rec & 0xFFFF;
          int rel = (rec >> 16) & 7;
          int cnt = ((unsigned)rec) >> 19;
          float s = 1.0f / (float)cnt;
          sc[u] = (ei < mb) ? s : 0.f;
          a[u] = *(const float4*)(w1 + (((size_t)(unsigned)(rel * NNODES + src)) << 6) + col);
        } else {
          sc[u] = 0.f;
          a[u] = make_float4(0.f, 0.f, 0.f, 0.f);
        }
      }
#pragma unroll
      for (int u = 0; u < 8; ++u) {
        acc.x = fmaf(a[u].x, sc[u], acc.x);
        acc.y = fmaf(a[u].y, sc[u], acc.y);
        acc.z = fmaf(a[u].z, sc[u], acc.z);
        acc.w = fmaf(a[u].w, sc[u], acc.w);
      }
    }
  }
#pragma unroll
  for (int off = 16; off < 64; off <<= 1) {
    acc.x += __shfl_xor(acc.x, off);
    acc.y += __shfl_xor(acc.y, off);
    acc.z += __shfl_xor(acc.z, off);
    acc.w += __shfl_xor(acc.w, off);
  }
  if (g == 0) {
    float4 r = *(const float4*)(root1 + (((size_t)wave) << 6) + col);
    float4 bz = *(const float4*)(bias1 + col);
    float4 v;
    v.x = elu1(acc.x + r.x + bz.x);
    v.y = elu1(acc.y + r.y + bz.y);
    v.z = elu1(acc.z + r.z + bz.z);
    v.w = elu1(acc.w + r.w + bz.w);
    *(float4*)(h1 + (((size_t)wave) << 6) + col) = v;
  }
}

// --- K5a: conv2 aggregation — wave per (node,rel) bin; float4 x 4-edge groups
__global__ __launch_bounds__(256) void conv2a_kernel(
    const int* __restrict__ binptr, const int* __restrict__ epo,
    const float* __restrict__ h1, float* __restrict__ agg, int nodeBase, int nloc) {
  int wv = blockIdx.x * 4 + (threadIdx.x >> 6);
  if (wv >= nloc * NREL) return;
  int lane = threadIdx.x & 63;
  int g = lane >> 4;
  int col = (lane & 15) << 2;
  int r = wv & 7;
  int bin = (nodeBase + (wv >> 3)) * NREL + r;
  int bb = binptr[bin], ee = binptr[bin + 1];
  float4 s = make_float4(0.f, 0.f, 0.f, 0.f);
  for (int e = bb; e < ee; e += 64) {
    int mb = min(64, ee - e);
    int q = epo[e + min(lane, mb - 1)];
    for (int j = 0; j < mb; j += 16) {  // 4 slots x 4 edges
      float4 a[4]; float vld[4];
#pragma unroll
      for (int u = 0; u < 4; ++u) {
        int e0 = j + u * 4;
        if (e0 < mb) {                     // wave-uniform branch
          int ei = e0 + g;
          int eic = min(ei, mb - 1);
          int src = __shfl(q, eic) & 0xFFFF;
          vld[u] = (ei < mb) ? 1.f : 0.f;
          a[u] = *(const float4*)(h1 + (((size_t)(unsigned)src) << 6) + col);
        } else {
          vld[u] = 0.f;
          a[u] = make_float4(0.f, 0.f, 0.f, 0.f);
        }
      }
#pragma unroll
      for (int u = 0; u < 4; ++u) {
        s.x = fmaf(a[u].x, vld[u], s.x);
        s.y = fmaf(a[u].y, vld[u], s.y);
        s.z = fmaf(a[u].z, vld[u], s.z);
        s.w = fmaf(a[u].w, vld[u], s.w);
      }
    }
  }
#pragma unroll
  for (int off = 16; off < 64; off <<= 1) {
    s.x += __shfl_xor(s.x, off);
    s.y += __shfl_xor(s.y, off);
    s.z += __shfl_xor(s.z, off);
    s.w += __shfl_xor(s.w, off);
  }
  if (g == 0) {
    float scl = (ee > bb) ? 1.0f / (float)(ee - bb) : 0.f;
    *(float4*)(agg + (((size_t)wv) << 6) + col) =
        make_float4(s.x * scl, s.y * scl, s.z * scl, s.w * scl);
  }
}

// --- K5b: conv2 transform + FUSED head: out = elu(h2) @ lin_w + lin_b --------
__global__ __launch_bounds__(256, 4) void conv2b_kernel(
    const float* __restrict__ agg, const float* __restrict__ h1,
    const float* __restrict__ w2, const float* __restrict__ root2,
    const float* __restrict__ bias2, const float* __restrict__ lin_w,
    const float* __restrict__ lin_b, float* __restrict__ out, int nodeBase) {
  __shared__ float sW[HID * HID];  // 16 KB (reused: W2 / root2 / {h-rows, lin_w})
  int t = threadIdx.x, lane = t & 63, wid = t >> 6;
  int ln0 = blockIdx.x * 8 + wid * 2;  // 8 local nodes/block, 2 per wave
  float bz = bias2[lane];
  float o0 = bz, o1 = bz;
  for (int r = 0; r < NREL; ++r) {
    if (r) __syncthreads();
#pragma unroll
    for (int i = 0; i < 4; ++i)
      *(float4*)(sW + t * 4 + i * 1024) = *(const float4*)(w2 + (r << 12) + t * 4 + i * 1024);
    __syncthreads();
    const float* a0 = agg + (((size_t)((ln0 + 0) * NREL + r)) << 6);  // wave-uniform -> s_load
    const float* a1 = agg + (((size_t)((ln0 + 1) * NREL + r)) << 6);
#pragma unroll 16
    for (int k = 0; k < HID; ++k) {
      float w = sW[(k << 6) + lane];
      o0 = fmaf(a0[k], w, o0);
      o1 = fmaf(a1[k], w, o1);
    }
  }
  __syncthreads();
#pragma unroll
  for (int i = 0; i < 4; ++i)
    *(float4*)(sW + t * 4 + i * 1024) = *(const float4*)(root2 + t * 4 + i * 1024);
  __syncthreads();
  int g0 = nodeBase + ln0;
  const float* r0p = h1 + ((size_t)(g0 + 0) << 6);  // wave-uniform -> s_load
  const float* r1p = h1 + ((size_t)(g0 + 1) << 6);
#pragma unroll 16
  for (int k = 0; k < HID; ++k) {
    float w = sW[(k << 6) + lane];
    o0 = fmaf(r0p[k], w, o0);
    o1 = fmaf(r1p[k], w, o1);
  }
  // ---- fused head: stage elu(h2) rows (pad-65) + lin_w in LDS, 128-thr dot --
  __syncthreads();
  int row0 = wid * 2;
  sW[row0 * 65 + lane] = elu1(o0);
  sW[(row0 + 1) * 65 + lane] = elu1(o1);
  float* lw = sW + 8 * 65;                       // 520..1544: lin_w [64][16]
  *(float4*)(lw + t * 4) = *(const float4*)(lin_w + t * 4);  // 256*4 = 1024
  __syncthreads();
  if (t < 8 * NCLS) {
    int n = t >> 4, c = t & 15;
    float accv = lin_b[c];
#pragma unroll 16
    for (int l = 0; l < HID; ++l)
      accv = fmaf(sW[n * 65 + l], lw[l * NCLS + c], accv);
    out[((size_t)(nodeBase + blockIdx.x * 8 + n)) * NCLS + c] = accv;
  }
}

extern "C" void kernel_launch(void* const* d_in, const int* in_sizes, int n_in,
                              void* d_out, int out_size, void* d_ws, size_t ws_size,
                              hipStream_t stream) {
  const int*   ei    = (const int*)d_in[0];
  const int*   et    = (const int*)d_in[1];
  const float* w1    = (const float*)d_in[3];
  const float* root1 = (const float*)d_in[4];
  const float* bias1 = (const float*)d_in[5];
  const float* w2    = (const float*)d_in[6];
  const float* root2 = (const float*)d_in[7];
  const float* bias2 = (const float*)d_in[8];
  const float* lin_w = (const float*)d_in[9];
  const float* lin_b = (const float*)d_in[10];
  float* out = (float*)d_out;

  // Workspace (R8 layout, ~29.2 MB peak):
  //   [0, 12.8M)    h1 (conv1 output) — overlaps cnt[0,1.6M)+epos[1.6M,8.0M)
  //   [12.8, ~14.4) binptr
  //   [~14.4, +4K)  lookback status
  //   then epo 6.4M, agg 8.4M (HALF chunk)
  char* ws = (char*)d_ws;
  float* h1     = (float*)ws;
  int*   cnt    = (int*)ws;
  int*   epos   = (int*)(ws + (size_t)NBINS * 4);
  char*  p      = ws + (size_t)NNODES * HID * 4;
  int*   binptr = (int*)p;  p += ((size_t)(NBINS + 1) * 4 + 255) & ~(size_t)255;
  unsigned long long* status = (unsigned long long*)p;
  p += ((size_t)NCHUNK * 8 + 255) & ~(size_t)255;
  int*   epo    = (int*)p;  p += (size_t)NEDGE * 4;
  float* agg    = (float*)p;

  hipMemsetAsync(cnt, 0, (size_t)NBINS * sizeof(int), stream);
  for (int s4 = 0; s4 < 4; ++s4)
    count_kernel<<<(QPART + 255) / 256, 256, 0, stream>>>(ei, et, cnt, epos, status,
                                                          s4 * QPART);
  scan_lb_kernel<<<NCHUNK, 256, 0, stream>>>(cnt, status, binptr);
  scatter_kernel<<<(NEDGE / 4 + 255) / 256, 256, 0, stream>>>(ei, et, epos, binptr, epo);
  for (int s4 = 0; s4 < 4; ++s4)
    conv1_kernel<<<C1PART / 4, 256, 0, stream>>>(binptr, epo, w1, root1, bias1, h1,
                                                 s4 * C1PART);
  for (int c = 0; c < 2; ++c) {
    conv2a_kernel<<<(HALF * NREL) / 4, 256, 0, stream>>>(binptr, epo, h1, agg, c * HALF, HALF);
    conv2b_kernel<<<HALF / 8, 256, 0, stream>>>(agg, h1, w2, root2, bias2, lin_w, lin_b,
                                                out, c * HALF);
  }
}

// Round 10
// 432.716 us; speedup vs baseline: 1.0055x; 1.0055x over previous
//
#include <hip/hip_runtime.h>

#define NNODES 50000
#define NREL   8
#define HID    64
#define NCLS   16
#define NEDGE  1600000
#define NTGT   8192
#define HALF   4096
#define NBINS  (NNODES * NREL)
#define CHUNK  1024
#define NCHUNK ((NBINS + CHUNK - 1) / CHUNK)   // 391

__device__ __forceinline__ float elu1(float x) { return x > 0.f ? x : expm1f(x); }

// packed edge record: src[15:0] | rel[18:16] | cnt[31:19]
__device__ __forceinline__ int pack_rec(int src, int rel, int cnt) {
  return src | (rel << 16) | (cnt << 19);
}

__device__ __forceinline__ unsigned long long ld_stat(unsigned long long* p) {
  return __hip_atomic_load(p, __ATOMIC_RELAXED, __HIP_MEMORY_SCOPE_AGENT);
}
__device__ __forceinline__ void st_stat(unsigned long long* p, unsigned long long v) {
  __hip_atomic_store(p, v, __ATOMIC_RELAXED, __HIP_MEMORY_SCOPE_AGENT);
}

// --- K1: per-(dst,rel) counts — FIRE-AND-FORGET atomics (no epos, no return
//         dependency); also clears the lookback status array ----------------
__global__ void count_kernel(const int* __restrict__ ei, const int* __restrict__ et,
                             int* __restrict__ cnt,
                             unsigned long long* __restrict__ status) {
  int gt = blockIdx.x * blockDim.x + threadIdx.x;
  if (gt < NCHUNK) status[gt] = 0;  // consumed by scan_lb (launched after us)
  int e4 = gt * 4;
  if (e4 >= NEDGE) return;
  int4 d = *(const int4*)(ei + NEDGE + e4);
  int4 r = *(const int4*)(et + e4);
  atomicAdd(&cnt[d.x * NREL + r.x], 1);   // results unused -> non-returning
  atomicAdd(&cnt[d.y * NREL + r.y], 1);
  atomicAdd(&cnt[d.z * NREL + r.z], 1);
  atomicAdd(&cnt[d.w * NREL + r.w], 1);
}

// --- K2: single-pass scan with decoupled lookback -> binptr (excl. starts) --
__global__ __launch_bounds__(256) void scan_lb_kernel(
    const int* __restrict__ cnt, unsigned long long* __restrict__ status,
    int* __restrict__ binptr) {
  __shared__ int sw[4];
  __shared__ int srun;
  __shared__ int sbase;
  int t = threadIdx.x, lane = t & 63, wid = t >> 6;
  int c = blockIdx.x;
  int i = c * CHUNK + t * 4;
  int4 cv = make_int4(0, 0, 0, 0);
  if (i < NBINS) cv = *(const int4*)(cnt + i);
  int p0 = cv.x, p1 = p0 + cv.y, p2 = p1 + cv.z, s = p2 + cv.w;
  int v = s;
#pragma unroll
  for (int off = 1; off < 64; off <<= 1) {
    int u = __shfl_up(v, off);
    if (lane >= off) v += u;
  }
  if (lane == 63) sw[wid] = v;
  __syncthreads();
  if (t == 0) {
    int run = 0;
#pragma unroll
    for (int j = 0; j < 4; ++j) { int x = sw[j]; sw[j] = run; run += x; }
    srun = run;
    unsigned long long f = (c == 0) ? 2ull : 1ull;
    st_stat(&status[c], (f << 62) | (unsigned)run);
    if (c == 0) sbase = 0;
  }
  __syncthreads();
  if (c > 0 && t < 64) {
    long long tot = 0;
    int back = c - 1;
    for (;;) {
      int idx = back - lane;
      unsigned long long st = (2ull << 62);
      if (idx >= 0) st = ld_stat(&status[idx]);
      int flag = (int)(st >> 62);
      bool isinc = (idx < 0) || (flag == 2);
      bool isval = (idx < 0) || (flag >= 1);
      unsigned long long incb = __ballot(isinc);
      unsigned long long valb = __ballot(isval);
      unsigned long long notval = ~valb;
      int firstinv = notval ? (__ffsll((long long)notval) - 1) : 64;
      int firstinc = incb ? (__ffsll((long long)incb) - 1) : 64;
      if (firstinc < firstinv) {
        int val = (lane <= firstinc) ? (int)(st & 0xFFFFFFFFu) : 0;
#pragma unroll
        for (int off = 32; off >= 1; off >>= 1) val += __shfl_xor(val, off);
        tot += val;
        break;
      } else if (firstinv > 0) {
        int val = (lane < firstinv) ? (int)(st & 0xFFFFFFFFu) : 0;
#pragma unroll
        for (int off = 32; off >= 1; off >>= 1) val += __shfl_xor(val, off);
        tot += val;
        back -= firstinv;
      } else {
        __builtin_amdgcn_s_sleep(2);
      }
    }
    if (lane == 0) {
      sbase = (int)tot;
      st_stat(&status[c], (2ull << 62) | (unsigned)((int)tot + srun));
    }
  }
  __syncthreads();
  int base = sbase;
  if (i < NBINS) {
    int excl = base + sw[wid] + (v - s);
    *(int4*)(binptr + i) = make_int4(excl, excl + p0, excl + p1, excl + p2);
  }
  if (c == 0 && t == 0) binptr[NBINS] = NEDGE;
}

// --- K3: scatter — pos = atomicAdd(&binptr[bin],1) (bucket-cursor in place);
//         scale denominator from cnt[bin] (stable during this kernel).
//         AFTER this kernel binptr[bin] == original binptr[bin+1], so
//         consumers read [binptr[bin-1], binptr[bin]) with 0 for bin 0. ------
__global__ void scatter_kernel(const int* __restrict__ ei, const int* __restrict__ et,
                               const int* __restrict__ cnt, int* __restrict__ binptr,
                               int* __restrict__ epo) {
  int e4 = (blockIdx.x * blockDim.x + threadIdx.x) * 4;
  if (e4 >= NEDGE) return;
  int4 sv = *(const int4*)(ei + e4);
  int4 dv = *(const int4*)(ei + NEDGE + e4);
  int4 rv = *(const int4*)(et + e4);
  int srcs[4] = {sv.x, sv.y, sv.z, sv.w};
  int dsts[4] = {dv.x, dv.y, dv.z, dv.w};
  int rels[4] = {rv.x, rv.y, rv.z, rv.w};
#pragma unroll
  for (int j = 0; j < 4; ++j) {
    int bin = dsts[j] * NREL + rels[j];
    int pos = atomicAdd(&binptr[bin], 1);
    int c = cnt[bin];  // c >= 1, < 2^13
    epo[pos] = pack_rec(srcs[j], rels[j], c);
  }
}

// --- K4: conv1 — wave per node; float4/lane x 4 edges per VMEM instruction;
//         shifted binptr convention (see K3) --------------------------------
__global__ __launch_bounds__(256) void conv1_kernel(
    const int* __restrict__ binptr, const int* __restrict__ epo,
    const float* __restrict__ w1, const float* __restrict__ root1,
    const float* __restrict__ bias1, float* __restrict__ h1) {
  int wave = blockIdx.x * 4 + (threadIdx.x >> 6);
  if (wave >= NNODES) return;
  int lane = threadIdx.x & 63;
  int g = lane >> 4;            // edge subgroup 0..3
  int col = (lane & 15) << 2;   // float4 column offset
  int base = wave * NREL;
  int b0 = (wave == 0) ? 0 : binptr[base - 1];
  int b8 = binptr[base + 7];
  float4 acc = make_float4(0.f, 0.f, 0.f, 0.f);
  for (int eb = b0; eb < b8; eb += 64) {
    int mb = min(64, b8 - eb);
    int q = epo[eb + min(lane, mb - 1)];
    for (int j = 0; j < mb; j += 32) {  // superbatch: 8 slots x 4 edges
      float4 a[8]; float sc[8];
#pragma unroll
      for (int u = 0; u < 8; ++u) {
        int e0 = j + u * 4;
        if (e0 < mb) {                       // wave-uniform branch
          int ei = e0 + g;
          int eic = min(ei, mb - 1);
          int rec = __shfl(q, eic);
          int src = rec & 0xFFFF;
          int rel = (rec >> 16) & 7;
          int cnt = ((unsigned)rec) >> 19;
          float s = 1.0f / (float)cnt;
          sc[u] = (ei < mb) ? s : 0.f;
          a[u] = *(const float4*)(w1 + (((size_t)(unsigned)(rel * NNODES + src)) << 6) + col);
        } else {
          sc[u] = 0.f;
          a[u] = make_float4(0.f, 0.f, 0.f, 0.f);
        }
      }
#pragma unroll
      for (int u = 0; u < 8; ++u) {
        acc.x = fmaf(a[u].x, sc[u], acc.x);
        acc.y = fmaf(a[u].y, sc[u], acc.y);
        acc.z = fmaf(a[u].z, sc[u], acc.z);
        acc.w = fmaf(a[u].w, sc[u], acc.w);
      }
    }
  }
#pragma unroll
  for (int off = 16; off < 64; off <<= 1) {
    acc.x += __shfl_xor(acc.x, off);
    acc.y += __shfl_xor(acc.y, off);
    acc.z += __shfl_xor(acc.z, off);
    acc.w += __shfl_xor(acc.w, off);
  }
  if (g == 0) {
    float4 r = *(const float4*)(root1 + (((size_t)wave) << 6) + col);
    float4 bz = *(const float4*)(bias1 + col);
    float4 v;
    v.x = elu1(acc.x + r.x + bz.x);
    v.y = elu1(acc.y + r.y + bz.y);
    v.z = elu1(acc.z + r.z + bz.z);
    v.w = elu1(acc.w + r.w + bz.w);
    *(float4*)(h1 + (((size_t)wave) << 6) + col) = v;
  }
}

// --- K5a: conv2 aggregation — wave per (node,rel) bin; shifted binptr --------
__global__ __launch_bounds__(256) void conv2a_kernel(
    const int* __restrict__ binptr, const int* __restrict__ epo,
    const float* __restrict__ h1, float* __restrict__ agg, int nodeBase, int nloc) {
  int wv = blockIdx.x * 4 + (threadIdx.x >> 6);
  if (wv >= nloc * NREL) return;
  int lane = threadIdx.x & 63;
  int g = lane >> 4;
  int col = (lane & 15) << 2;
  int r = wv & 7;
  int bin = (nodeBase + (wv >> 3)) * NREL + r;
  int bb = (bin == 0) ? 0 : binptr[bin - 1];
  int ee = binptr[bin];
  float4 s = make_float4(0.f, 0.f, 0.f, 0.f);
  for (int e = bb; e < ee; e += 64) {
    int mb = min(64, ee - e);
    int q = epo[e + min(lane, mb - 1)];
    for (int j = 0; j < mb; j += 16) {  // 4 slots x 4 edges
      float4 a[4]; float vld[4];
#pragma unroll
      for (int u = 0; u < 4; ++u) {
        int e0 = j + u * 4;
        if (e0 < mb) {                     // wave-uniform branch
          int ei = e0 + g;
          int eic = min(ei, mb - 1);
          int src = __shfl(q, eic) & 0xFFFF;
          vld[u] = (ei < mb) ? 1.f : 0.f;
          a[u] = *(const float4*)(h1 + (((size_t)(unsigned)src) << 6) + col);
        } else {
          vld[u] = 0.f;
          a[u] = make_float4(0.f, 0.f, 0.f, 0.f);
        }
      }
#pragma unroll
      for (int u = 0; u < 4; ++u) {
        s.x = fmaf(a[u].x, vld[u], s.x);
        s.y = fmaf(a[u].y, vld[u], s.y);
        s.z = fmaf(a[u].z, vld[u], s.z);
        s.w = fmaf(a[u].w, vld[u], s.w);
      }
    }
  }
#pragma unroll
  for (int off = 16; off < 64; off <<= 1) {
    s.x += __shfl_xor(s.x, off);
    s.y += __shfl_xor(s.y, off);
    s.z += __shfl_xor(s.z, off);
    s.w += __shfl_xor(s.w, off);
  }
  if (g == 0) {
    float scl = (ee > bb) ? 1.0f / (float)(ee - bb) : 0.f;
    *(float4*)(agg + (((size_t)wv) << 6) + col) =
        make_float4(s.x * scl, s.y * scl, s.z * scl, s.w * scl);
  }
}

// --- K5b: conv2 transform + FUSED head: out = elu(h2) @ lin_w + lin_b --------
__global__ __launch_bounds__(256, 4) void conv2b_kernel(
    const float* __restrict__ agg, const float* __restrict__ h1,
    const float* __restrict__ w2, const float* __restrict__ root2,
    const float* __restrict__ bias2, const float* __restrict__ lin_w,
    const float* __restrict__ lin_b, float* __restrict__ out, int nodeBase) {
  __shared__ float sW[HID * HID];  // 16 KB (reused: W2 / root2 / {h-rows, lin_w})
  int t = threadIdx.x, lane = t & 63, wid = t >> 6;
  int ln0 = blockIdx.x * 8 + wid * 2;  // 8 local nodes/block, 2 per wave
  float bz = bias2[lane];
  float o0 = bz, o1 = bz;
  for (int r = 0; r < NREL; ++r) {
    if (r) __syncthreads();
#pragma unroll
    for (int i = 0; i < 4; ++i)
      *(float4*)(sW + t * 4 + i * 1024) = *(const float4*)(w2 + (r << 12) + t * 4 + i * 1024);
    __syncthreads();
    const float* a0 = agg + (((size_t)((ln0 + 0) * NREL + r)) << 6);  // wave-uniform -> s_load
    const float* a1 = agg + (((size_t)((ln0 + 1) * NREL + r)) << 6);
#pragma unroll 16
    for (int k = 0; k < HID; ++k) {
      float w = sW[(k << 6) + lane];
      o0 = fmaf(a0[k], w, o0);
      o1 = fmaf(a1[k], w, o1);
    }
  }
  __syncthreads();
#pragma unroll
  for (int i = 0; i < 4; ++i)
    *(float4*)(sW + t * 4 + i * 1024) = *(const float4*)(root2 + t * 4 + i * 1024);
  __syncthreads();
  int g0 = nodeBase + ln0;
  const float* r0p = h1 + ((size_t)(g0 + 0) << 6);  // wave-uniform -> s_load
  const float* r1p = h1 + ((size_t)(g0 + 1) << 6);
#pragma unroll 16
  for (int k = 0; k < HID; ++k) {
    float w = sW[(k << 6) + lane];
    o0 = fmaf(r0p[k], w, o0);
    o1 = fmaf(r1p[k], w, o1);
  }
  // ---- fused head: stage elu(h2) rows (pad-65) + lin_w in LDS, 128-thr dot --
  __syncthreads();
  int row0 = wid * 2;
  sW[row0 * 65 + lane] = elu1(o0);
  sW[(row0 + 1) * 65 + lane] = elu1(o1);
  float* lw = sW + 8 * 65;                       // 520..1544: lin_w [64][16]
  *(float4*)(lw + t * 4) = *(const float4*)(lin_w + t * 4);  // 256*4 = 1024
  __syncthreads();
  if (t < 8 * NCLS) {
    int n = t >> 4, c = t & 15;
    float accv = lin_b[c];
#pragma unroll 16
    for (int l = 0; l < HID; ++l)
      accv = fmaf(sW[n * 65 + l], lw[l * NCLS + c], accv);
    out[((size_t)(nodeBase + blockIdx.x * 8 + n)) * NCLS + c] = accv;
  }
}

extern "C" void kernel_launch(void* const* d_in, const int* in_sizes, int n_in,
                              void* d_out, int out_size, void* d_ws, size_t ws_size,
                              hipStream_t stream) {
  const int*   ei    = (const int*)d_in[0];
  const int*   et    = (const int*)d_in[1];
  const float* w1    = (const float*)d_in[3];
  const float* root1 = (const float*)d_in[4];
  const float* bias1 = (const float*)d_in[5];
  const float* w2    = (const float*)d_in[6];
  const float* root2 = (const float*)d_in[7];
  const float* bias2 = (const float*)d_in[8];
  const float* lin_w = (const float*)d_in[9];
  const float* lin_b = (const float*)d_in[10];
  float* out = (float*)d_out;

  // Workspace:
  //   [0, 12.8M)    h1 (conv1 output) — overlaps cnt[0,1.6M) (cnt dead after
  //                 scatter, h1 written by conv1 which runs after scatter)
  //   [12.8, ~14.4) binptr
  //   [~14.4, +4K)  lookback status
  //   then epo 6.4M, agg (16.8M single-pass or 8.4M two-pass)
  char* ws = (char*)d_ws;
  float* h1     = (float*)ws;
  int*   cnt    = (int*)ws;
  char*  p      = ws + (size_t)NNODES * HID * 4;
  int*   binptr = (int*)p;  p += ((size_t)(NBINS + 1) * 4 + 255) & ~(size_t)255;
  unsigned long long* status = (unsigned long long*)p;
  p += ((size_t)NCHUNK * 8 + 255) & ~(size_t)255;
  int*   epo    = (int*)p;  p += (size_t)NEDGE * 4;
  float* agg    = (float*)p;
  size_t fixed  = (size_t)(p - ws);
  // single conv2 pass (chunk=8192) if ws allows, else two passes of 4096.
  // ws_size constant across calls -> branch stable under graph capture.
  int chunk = (fixed + (size_t)NTGT * NREL * HID * 4 <= ws_size) ? NTGT : HALF;

  hipMemsetAsync(cnt, 0, (size_t)NBINS * sizeof(int), stream);
  count_kernel<<<(NEDGE / 4 + 255) / 256, 256, 0, stream>>>(ei, et, cnt, status);
  scan_lb_kernel<<<NCHUNK, 256, 0, stream>>>(cnt, status, binptr);
  scatter_kernel<<<(NEDGE / 4 + 255) / 256, 256, 0, stream>>>(ei, et, cnt, binptr, epo);
  conv1_kernel<<<(NNODES + 3) / 4, 256, 0, stream>>>(binptr, epo, w1, root1, bias1, h1);
  for (int c = 0; c < NTGT / chunk; ++c) {
    conv2a_kernel<<<(chunk * NREL) / 4, 256, 0, stream>>>(binptr, epo, h1, agg, c * chunk, chunk);
    conv2b_kernel<<<chunk / 8, 256, 0, stream>>>(agg, h1, w2, root2, bias2, lin_w, lin_b,
                                                 out, c * chunk);
  }
}

// Round 11
// 401.163 us; speedup vs baseline: 1.0846x; 1.0787x over previous
//
#include <hip/hip_runtime.h>

#define NNODES 50000
#define NREL   8
#define HID    64
#define NCLS   16
#define NEDGE  1600000
#define NTGT   8192
#define HALF   4096
#define NBINS  (NNODES * NREL)
#define CHUNK  1024
#define NCHUNK ((NBINS + CHUNK - 1) / CHUNK)   // 391

__device__ __forceinline__ float elu1(float x) { return x > 0.f ? x : expm1f(x); }

// packed edge record: src[15:0] | rel[18:16] | cnt[31:19]
__device__ __forceinline__ int pack_rec(int src, int rel, int cnt) {
  return src | (rel << 16) | (cnt << 19);
}

__device__ __forceinline__ unsigned long long ld_stat(unsigned long long* p) {
  return __hip_atomic_load(p, __ATOMIC_RELAXED, __HIP_MEMORY_SCOPE_AGENT);
}
__device__ __forceinline__ void st_stat(unsigned long long* p, unsigned long long v) {
  __hip_atomic_store(p, v, __ATOMIC_RELAXED, __HIP_MEMORY_SCOPE_AGENT);
}

// --- K1: per-(dst,rel) counts; epos[e] = slot within bin (R8-proven form);
//         also clears the lookback status array -----------------------------
__global__ void count_kernel(const int* __restrict__ ei, const int* __restrict__ et,
                             int* __restrict__ cnt, int* __restrict__ epos,
                             unsigned long long* __restrict__ status) {
  int gt = blockIdx.x * blockDim.x + threadIdx.x;
  if (gt < NCHUNK) status[gt] = 0;  // consumed by scan_lb (launched after us)
  int e4 = gt * 4;
  if (e4 >= NEDGE) return;
  int4 d = *(const int4*)(ei + NEDGE + e4);
  int4 r = *(const int4*)(et + e4);
  int4 p;
  p.x = atomicAdd(&cnt[d.x * NREL + r.x], 1);
  p.y = atomicAdd(&cnt[d.y * NREL + r.y], 1);
  p.z = atomicAdd(&cnt[d.z * NREL + r.z], 1);
  p.w = atomicAdd(&cnt[d.w * NREL + r.w], 1);
  *(int4*)(epos + e4) = p;
}

// --- K2: single-pass scan with decoupled lookback -> binptr -----------------
__global__ __launch_bounds__(256) void scan_lb_kernel(
    const int* __restrict__ cnt, unsigned long long* __restrict__ status,
    int* __restrict__ binptr) {
  __shared__ int sw[4];
  __shared__ int srun;
  __shared__ int sbase;
  int t = threadIdx.x, lane = t & 63, wid = t >> 6;
  int c = blockIdx.x;
  int i = c * CHUNK + t * 4;
  int4 cv = make_int4(0, 0, 0, 0);
  if (i < NBINS) cv = *(const int4*)(cnt + i);
  int p0 = cv.x, p1 = p0 + cv.y, p2 = p1 + cv.z, s = p2 + cv.w;
  int v = s;
#pragma unroll
  for (int off = 1; off < 64; off <<= 1) {
    int u = __shfl_up(v, off);
    if (lane >= off) v += u;
  }
  if (lane == 63) sw[wid] = v;
  __syncthreads();
  if (t == 0) {
    int run = 0;
#pragma unroll
    for (int j = 0; j < 4; ++j) { int x = sw[j]; sw[j] = run; run += x; }
    srun = run;
    unsigned long long f = (c == 0) ? 2ull : 1ull;
    st_stat(&status[c], (f << 62) | (unsigned)run);
    if (c == 0) sbase = 0;
  }
  __syncthreads();
  if (c > 0 && t < 64) {
    long long tot = 0;
    int back = c - 1;
    for (;;) {
      int idx = back - lane;
      unsigned long long st = (2ull << 62);
      if (idx >= 0) st = ld_stat(&status[idx]);
      int flag = (int)(st >> 62);
      bool isinc = (idx < 0) || (flag == 2);
      bool isval = (idx < 0) || (flag >= 1);
      unsigned long long incb = __ballot(isinc);
      unsigned long long valb = __ballot(isval);
      unsigned long long notval = ~valb;
      int firstinv = notval ? (__ffsll((long long)notval) - 1) : 64;
      int firstinc = incb ? (__ffsll((long long)incb) - 1) : 64;
      if (firstinc < firstinv) {
        int val = (lane <= firstinc) ? (int)(st & 0xFFFFFFFFu) : 0;
#pragma unroll
        for (int off = 32; off >= 1; off >>= 1) val += __shfl_xor(val, off);
        tot += val;
        break;
      } else if (firstinv > 0) {
        int val = (lane < firstinv) ? (int)(st & 0xFFFFFFFFu) : 0;
#pragma unroll
        for (int off = 32; off >= 1; off >>= 1) val += __shfl_xor(val, off);
        tot += val;
        back -= firstinv;
      } else {
        __builtin_amdgcn_s_sleep(2);
      }
    }
    if (lane == 0) {
      sbase = (int)tot;
      st_stat(&status[c], (2ull << 62) | (unsigned)((int)tot + srun));
    }
  }
  __syncthreads();
  int base = sbase;
  if (i < NBINS) {
    int excl = base + sw[wid] + (v - s);
    *(int4*)(binptr + i) = make_int4(excl, excl + p0, excl + p1, excl + p2);
  }
  if (c == 0 && t == 0) binptr[NBINS] = NEDGE;
}

// --- K3: scatter -> epo[pos] = packed {src,rel,cnt}; dependency-free stores --
__global__ void scatter_kernel(const int* __restrict__ ei, const int* __restrict__ et,
                               const int* __restrict__ epos, const int* __restrict__ binptr,
                               int* __restrict__ epo) {
  int e4 = (blockIdx.x * blockDim.x + threadIdx.x) * 4;
  if (e4 >= NEDGE) return;
  int4 sv = *(const int4*)(ei + e4);
  int4 dv = *(const int4*)(ei + NEDGE + e4);
  int4 rv = *(const int4*)(et + e4);
  int4 pv = *(const int4*)(epos + e4);
  int srcs[4] = {sv.x, sv.y, sv.z, sv.w};
  int dsts[4] = {dv.x, dv.y, dv.z, dv.w};
  int rels[4] = {rv.x, rv.y, rv.z, rv.w};
  int poss[4] = {pv.x, pv.y, pv.z, pv.w};
#pragma unroll
  for (int j = 0; j < 4; ++j) {
    int bin = dsts[j] * NREL + rels[j];
    int b = binptr[bin];
    int c = binptr[bin + 1] - b;  // c >= 1, < 2^13
    epo[b + poss[j]] = pack_rec(srcs[j], rels[j], c);
  }
}

// --- K4: conv1 — wave per node; float4/lane x 4 edges per VMEM instruction ---
__global__ __launch_bounds__(256) void conv1_kernel(
    const int* __restrict__ binptr, const int* __restrict__ epo,
    const float* __restrict__ w1, const float* __restrict__ root1,
    const float* __restrict__ bias1, float* __restrict__ h1) {
  int wave = blockIdx.x * 4 + (threadIdx.x >> 6);
  if (wave >= NNODES) return;
  int lane = threadIdx.x & 63;
  int g = lane >> 4;            // edge subgroup 0..3
  int col = (lane & 15) << 2;   // float4 column offset
  int b0 = binptr[wave * NREL], b8 = binptr[wave * NREL + NREL];
  float4 acc = make_float4(0.f, 0.f, 0.f, 0.f);
  for (int eb = b0; eb < b8; eb += 64) {
    int mb = min(64, b8 - eb);
    int q = epo[eb + min(lane, mb - 1)];
    for (int j = 0; j < mb; j += 32) {  // superbatch: 8 slots x 4 edges
      float4 a[8]; float sc[8];
#pragma unroll
      for (int u = 0; u < 8; ++u) {
        int e0 = j + u * 4;
        if (e0 < mb) {                       // wave-uniform branch
          int ei = e0 + g;
          int eic = min(ei, mb - 1);
          int rec = __shfl(q, eic);
          int src = rec & 0xFFFF;
          int rel = (rec >> 16) & 7;
          int cnt = ((unsigned)rec) >> 19;
          float s = 1.0f / (float)cnt;
          sc[u] = (ei < mb) ? s : 0.f;
          a[u] = *(const float4*)(w1 + (((size_t)(unsigned)(rel * NNODES + src)) << 6) + col);
        } else {
          sc[u] = 0.f;
          a[u] = make_float4(0.f, 0.f, 0.f, 0.f);
        }
      }
#pragma unroll
      for (int u = 0; u < 8; ++u) {
        acc.x = fmaf(a[u].x, sc[u], acc.x);
        acc.y = fmaf(a[u].y, sc[u], acc.y);
        acc.z = fmaf(a[u].z, sc[u], acc.z);
        acc.w = fmaf(a[u].w, sc[u], acc.w);
      }
    }
  }
#pragma unroll
  for (int off = 16; off < 64; off <<= 1) {
    acc.x += __shfl_xor(acc.x, off);
    acc.y += __shfl_xor(acc.y, off);
    acc.z += __shfl_xor(acc.z, off);
    acc.w += __shfl_xor(acc.w, off);
  }
  if (g == 0) {
    float4 r = *(const float4*)(root1 + (((size_t)wave) << 6) + col);
    float4 bz = *(const float4*)(bias1 + col);
    float4 v;
    v.x = elu1(acc.x + r.x + bz.x);
    v.y = elu1(acc.y + r.y + bz.y);
    v.z = elu1(acc.z + r.z + bz.z);
    v.w = elu1(acc.w + r.w + bz.w);
    *(float4*)(h1 + (((size_t)wave) << 6) + col) = v;
  }
}

// --- K5a: conv2 aggregation — ONE WAVE PER NODE (8 bins, ~32 edges): conv1's
//          proven gather shape; per-relation split via compile-time-unrolled
//          predicated FMA into acc[8] (static indexing, no scratch) ----------
__global__ __launch_bounds__(256) void conv2a_kernel(
    const int* __restrict__ binptr, const int* __restrict__ epo,
    const float* __restrict__ h1, float* __restrict__ agg, int nodeBase, int nloc) {
  int wv = blockIdx.x * 4 + (threadIdx.x >> 6);  // local node
  if (wv >= nloc) return;
  int lane = threadIdx.x & 63;
  int g = lane >> 4;
  int col = (lane & 15) << 2;
  int node = nodeBase + wv;
  int b0 = binptr[node * NREL], b8 = binptr[node * NREL + NREL];
  float4 acc[NREL];
#pragma unroll
  for (int r = 0; r < NREL; ++r) acc[r] = make_float4(0.f, 0.f, 0.f, 0.f);
  for (int eb = b0; eb < b8; eb += 64) {
    int mb = min(64, b8 - eb);
    int q = epo[eb + min(lane, mb - 1)];
    for (int j = 0; j < mb; j += 32) {  // 8 slots x 4 edges
      float4 a[8]; float sc[8]; int rl[8];
#pragma unroll
      for (int u = 0; u < 8; ++u) {
        int e0 = j + u * 4;
        if (e0 < mb) {                     // wave-uniform branch
          int ei = e0 + g;
          int eic = min(ei, mb - 1);
          int rec = __shfl(q, eic);
          int src = rec & 0xFFFF;
          rl[u] = (rec >> 16) & 7;
          int cnt = ((unsigned)rec) >> 19;
          sc[u] = (ei < mb) ? 1.0f / (float)cnt : 0.f;  // per-edge 1/|bin|
          a[u] = *(const float4*)(h1 + (((size_t)(unsigned)src) << 6) + col);
        } else {
          sc[u] = 0.f; rl[u] = 0;
          a[u] = make_float4(0.f, 0.f, 0.f, 0.f);
        }
      }
#pragma unroll
      for (int u = 0; u < 8; ++u) {
#pragma unroll
        for (int r = 0; r < NREL; ++r) {
          float m = (rl[u] == r) ? sc[u] : 0.f;
          acc[r].x = fmaf(a[u].x, m, acc[r].x);
          acc[r].y = fmaf(a[u].y, m, acc[r].y);
          acc[r].z = fmaf(a[u].z, m, acc[r].z);
          acc[r].w = fmaf(a[u].w, m, acc[r].w);
        }
      }
    }
  }
#pragma unroll
  for (int r = 0; r < NREL; ++r) {
#pragma unroll
    for (int off = 16; off < 64; off <<= 1) {
      acc[r].x += __shfl_xor(acc[r].x, off);
      acc[r].y += __shfl_xor(acc[r].y, off);
      acc[r].z += __shfl_xor(acc[r].z, off);
      acc[r].w += __shfl_xor(acc[r].w, off);
    }
  }
  if (g == 0) {
#pragma unroll
    for (int r = 0; r < NREL; ++r)
      *(float4*)(agg + (((size_t)(wv * NREL + r)) << 6) + col) = acc[r];
  }
}

// --- K5b: conv2 transform + FUSED head: out = elu(h2) @ lin_w + lin_b --------
__global__ __launch_bounds__(256, 4) void conv2b_kernel(
    const float* __restrict__ agg, const float* __restrict__ h1,
    const float* __restrict__ w2, const float* __restrict__ root2,
    const float* __restrict__ bias2, const float* __restrict__ lin_w,
    const float* __restrict__ lin_b, float* __restrict__ out, int nodeBase) {
  __shared__ float sW[HID * HID];  // 16 KB (reused: W2 / root2 / {h-rows, lin_w})
  int t = threadIdx.x, lane = t & 63, wid = t >> 6;
  int ln0 = blockIdx.x * 8 + wid * 2;  // 8 local nodes/block, 2 per wave
  float bz = bias2[lane];
  float o0 = bz, o1 = bz;
  for (int r = 0; r < NREL; ++r) {
    if (r) __syncthreads();
#pragma unroll
    for (int i = 0; i < 4; ++i)
      *(float4*)(sW + t * 4 + i * 1024) = *(const float4*)(w2 + (r << 12) + t * 4 + i * 1024);
    __syncthreads();
    const float* a0 = agg + (((size_t)((ln0 + 0) * NREL + r)) << 6);  // wave-uniform -> s_load
    const float* a1 = agg + (((size_t)((ln0 + 1) * NREL + r)) << 6);
#pragma unroll 16
    for (int k = 0; k < HID; ++k) {
      float w = sW[(k << 6) + lane];
      o0 = fmaf(a0[k], w, o0);
      o1 = fmaf(a1[k], w, o1);
    }
  }
  __syncthreads();
#pragma unroll
  for (int i = 0; i < 4; ++i)
    *(float4*)(sW + t * 4 + i * 1024) = *(const float4*)(root2 + t * 4 + i * 1024);
  __syncthreads();
  int g0 = nodeBase + ln0;
  const float* r0p = h1 + ((size_t)(g0 + 0) << 6);  // wave-uniform -> s_load
  const float* r1p = h1 + ((size_t)(g0 + 1) << 6);
#pragma unroll 16
  for (int k = 0; k < HID; ++k) {
    float w = sW[(k << 6) + lane];
    o0 = fmaf(r0p[k], w, o0);
    o1 = fmaf(r1p[k], w, o1);
  }
  // ---- fused head: stage elu(h2) rows (pad-65) + lin_w in LDS, 128-thr dot --
  __syncthreads();
  int row0 = wid * 2;
  sW[row0 * 65 + lane] = elu1(o0);
  sW[(row0 + 1) * 65 + lane] = elu1(o1);
  float* lw = sW + 8 * 65;                       // 520..1544: lin_w [64][16]
  *(float4*)(lw + t * 4) = *(const float4*)(lin_w + t * 4);  // 256*4 = 1024
  __syncthreads();
  if (t < 8 * NCLS) {
    int n = t >> 4, c = t & 15;
    float accv = lin_b[c];
#pragma unroll 16
    for (int l = 0; l < HID; ++l)
      accv = fmaf(sW[n * 65 + l], lw[l * NCLS + c], accv);
    out[((size_t)(nodeBase + blockIdx.x * 8 + n)) * NCLS + c] = accv;
  }
}

extern "C" void kernel_launch(void* const* d_in, const int* in_sizes, int n_in,
                              void* d_out, int out_size, void* d_ws, size_t ws_size,
                              hipStream_t stream) {
  const int*   ei    = (const int*)d_in[0];
  const int*   et    = (const int*)d_in[1];
  const float* w1    = (const float*)d_in[3];
  const float* root1 = (const float*)d_in[4];
  const float* bias1 = (const float*)d_in[5];
  const float* w2    = (const float*)d_in[6];
  const float* root2 = (const float*)d_in[7];
  const float* bias2 = (const float*)d_in[8];
  const float* lin_w = (const float*)d_in[9];
  const float* lin_b = (const float*)d_in[10];
  float* out = (float*)d_out;

  // Workspace (R8-proven layout):
  //   [0, 12.8M)    h1 (conv1 output) — overlaps cnt[0,1.6M)+epos[1.6M,8.0M),
  //                 both dead before conv1 writes
  //   [12.8, ~14.4) binptr
  //   [~14.4, +4K)  lookback status
  //   then epo 6.4M, agg (16.8M single-pass or 8.4M two-pass)
  char* ws = (char*)d_ws;
  float* h1     = (float*)ws;
  int*   cnt    = (int*)ws;
  int*   epos   = (int*)(ws + (size_t)NBINS * 4);
  char*  p      = ws + (size_t)NNODES * HID * 4;
  int*   binptr = (int*)p;  p += ((size_t)(NBINS + 1) * 4 + 255) & ~(size_t)255;
  unsigned long long* status = (unsigned long long*)p;
  p += ((size_t)NCHUNK * 8 + 255) & ~(size_t)255;
  int*   epo    = (int*)p;  p += (size_t)NEDGE * 4;
  float* agg    = (float*)p;
  size_t fixed  = (size_t)(p - ws);
  // single conv2 pass (chunk=8192) if ws allows, else two passes of 4096.
  // ws_size constant across calls -> branch stable under graph capture.
  int chunk = (fixed + (size_t)NTGT * NREL * HID * 4 <= ws_size) ? NTGT : HALF;

  hipMemsetAsync(cnt, 0, (size_t)NBINS * sizeof(int), stream);
  count_kernel<<<(NEDGE / 4 + 255) / 256, 256, 0, stream>>>(ei, et, cnt, epos, status);
  scan_lb_kernel<<<NCHUNK, 256, 0, stream>>>(cnt, status, binptr);
  scatter_kernel<<<(NEDGE / 4 + 255) / 256, 256, 0, stream>>>(ei, et, epos, binptr, epo);
  conv1_kernel<<<(NNODES + 3) / 4, 256, 0, stream>>>(binptr, epo, w1, root1, bias1, h1);
  for (int c = 0; c < NTGT / chunk; ++c) {
    conv2a_kernel<<<(chunk + 3) / 4, 256, 0, stream>>>(binptr, epo, h1, agg, c * chunk, chunk);
    conv2b_kernel<<<chunk / 8, 256, 0, stream>>>(agg, h1, w2, root2, bias2, lin_w, lin_b,
                                                 out, c * chunk);
  }
}